// Round 6
// baseline (235.542 us; speedup 1.0000x reference)
//
#include <hip/hip_runtime.h>

// Steerable pyramid, depthwise convs, NHWC fp32, C=16 (= 4 x float4).
// Branch-free convs over zero-padded workspace buffers.
// 4 output pixels per thread (sliding-window column reuse).
// XCD-aware scheduling: n = blockIdx & 7 (8 images -> 8 XCDs), y swept in
// order per XCD so the dy-loop row window stays resident in that XCD's L2.
// All conv outputs use NON-TEMPORAL stores so the write streams don't
// evict the L2-resident input row window (write-allocate thrash).

static __device__ __forceinline__ float4 f4z() { return make_float4(0.f, 0.f, 0.f, 0.f); }

static __device__ __forceinline__ float4 fmaf4(float f, float4 v, float4 a) {
    a.x = fmaf(f, v.x, a.x);
    a.y = fmaf(f, v.y, a.y);
    a.z = fmaf(f, v.z, a.z);
    a.w = fmaf(f, v.w, a.w);
    return a;
}

typedef __attribute__((ext_vector_type(4))) float f32x4;

static __device__ __forceinline__ void nt_store(float4* p, float4 v) {
    __builtin_nontemporal_store(*(const f32x4*)&v, (f32x4*)p);
}

// ---------------------------------------------------------------- pad helpers

// Copy 256x256 image into 264x264 buffer (pad 4), zero border. n = b&7.
__global__ __launch_bounds__(256) void pad_copy_img(
    const float4* __restrict__ src, float4* __restrict__ dst)
{
    const int W = 256, P = 4, Wp = 264;
    int n = blockIdx.x & 7;
    int q = blockIdx.x >> 3;                 // 1089 per n
    int e = q * 256 + threadIdx.x;           // < 264*264*4 exactly
    int c4 = e & 3;
    int pix = e >> 2;                        // < 264*264
    int yp = pix / Wp;
    int xp = pix - yp * Wp;
    int y = yp - P, x = xp - P;
    bool ok = ((unsigned)y < (unsigned)W) && ((unsigned)x < (unsigned)W);
    int yc = min(max(y, 0), W - 1), xc = min(max(x, 0), W - 1);
    float4 v = src[(((n * W + yc) * W + xc) << 2) + c4];
    if (!ok) v = f4z();
    dst[((size_t)n * Wp * Wp + pix) * 4 + c4] = v;
}

// Zero the 8-wide pad borders of all four lo buffers in ONE launch.
// Block ranges: L0(W=256):1056, L1(128):544, L2(64):288, L3(32):160 -> 2048 total.
__global__ __launch_bounds__(256) void zero_pads_all(
    float4* __restrict__ L0, float4* __restrict__ L1,
    float4* __restrict__ L2, float4* __restrict__ L3)
{
    int b = blockIdx.x;
    float4* buf; int W;
    if (b < 1056)      { buf = L0; W = 256; }
    else if (b < 1600) { buf = L1; W = 128; b -= 1056; }
    else if (b < 1888) { buf = L2; W = 64;  b -= 1600; }
    else               { buf = L3; W = 32;  b -= 1888; }
    int Wp = W + 16;
    int perN = 16 * Wp + 16 * W;
    int tid = b * 256 + threadIdx.x;
    int c4 = tid & 3;
    int p  = tid >> 2;
    int n  = p / perN;
    int r  = p - n * perN;
    int y, x;
    if (r < 16 * Wp) {
        int row = r / Wp;
        x = r - row * Wp;
        y = (row < 8) ? row : (W + row);
    } else {
        int q = r - 16 * Wp;
        y = 8 + (q >> 4);
        int xi = q & 15;
        x = (xi < 8) ? xi : (Wp - 16 + xi);
    }
    buf[((size_t)(n * Wp + y) * Wp + x) * 4 + c4] = f4z();
}

// ---------------------------------------------------------------- convs

// hi0 + lo0 from padded image (pad 4). 4 px/thread. One y row per block.
// n = b&7, y = b>>3.
__global__ __launch_bounds__(256) void conv9_dual4(
    const float4* __restrict__ in,   // 264 wide, pad 4
    float4* __restrict__ hi0,        // flat 256
    float4* __restrict__ lo0,        // 272 wide, pad 8
    const float* __restrict__ fh, const float* __restrict__ fl)
{
    const int W = 256, Wp = 264;
    int n = blockIdx.x & 7;
    int y = blockIdx.x >> 3;
    int t = threadIdx.x;
    int c4 = t & 3;
    int xg = t >> 2;                 // 0..63
    int x0 = xg * 4;
    const float4* row = in + ((size_t)(n * Wp + y) * Wp + x0) * 4 + c4;

    float4 ah[4], al[4];
    #pragma unroll
    for (int p = 0; p < 4; ++p) { ah[p] = f4z(); al[p] = f4z(); }

    #pragma unroll 1
    for (int dy = 0; dy < 9; ++dy) {
        float4 v[12];
        #pragma unroll
        for (int j = 0; j < 12; ++j) v[j] = row[j * 4];
        #pragma unroll
        for (int dx = 0; dx < 9; ++dx) {
            int tt = dy * 9 + dx;
            float wh = fh[tt], wl = fl[tt];
            #pragma unroll
            for (int p = 0; p < 4; ++p) {
                ah[p] = fmaf4(wh, v[p + dx], ah[p]);
                al[p] = fmaf4(wl, v[p + dx], al[p]);
            }
        }
        row += Wp * 4;
    }
    #pragma unroll
    for (int p = 0; p < 4; ++p) {
        nt_store(&hi0[((size_t)(n * W + y) * W + x0 + p) * 4 + c4], ah[p]);
        nt_store(&lo0[((size_t)(n * 272 + y + 8) * 272 + x0 + p + 8) * 4 + c4], al[p]);
    }
}

// Fused per-scale kernel. n = b&7; q = b>>3. q < bandsPerN -> 9x9 quad bands,
// else 17x17 stride-2 downsample. Input: padded (pad 8) lo, Wp = W+16.
// 4 px/thread; y swept in order per XCD.
template <int LOGW>
__global__ __launch_bounds__(256) void scale_fused(
    const float4* __restrict__ in,
    float4* __restrict__ b0, float4* __restrict__ b1,
    float4* __restrict__ b2, float4* __restrict__ b3,
    float4* __restrict__ lo_out,
    const float* __restrict__ bf,    // 4*81 contiguous
    const float* __restrict__ lf,    // 17*17
    int outPad)
{
    const int W = 1 << LOGW, Wp = W + 16;
    const int bandsPerN = (W * W) >> 8;      // blocks per image for bands
    int n = blockIdx.x & 7;
    int q = blockIdx.x >> 3;
    int t = threadIdx.x;
    int c4 = t & 3;

    if (q < bandsPerN) {
        int xg = (t >> 2) & (W / 4 - 1);
        int ry = t >> LOGW;                  // rows-per-block = 256/W
        int y  = q * (256 >> LOGW) + ry;
        int x0 = xg * 4;
        const float4* row = in + ((size_t)(n * Wp + y + 4) * Wp + (x0 + 4)) * 4 + c4;

        float4 acc[4][4];
        #pragma unroll
        for (int p = 0; p < 4; ++p)
            #pragma unroll
            for (int f = 0; f < 4; ++f) acc[p][f] = f4z();

        #pragma unroll 1
        for (int dy = 0; dy < 9; ++dy) {
            float4 v[12];
            #pragma unroll
            for (int j = 0; j < 12; ++j) v[j] = row[j * 4];
            #pragma unroll
            for (int dx = 0; dx < 9; ++dx) {
                int tt = dy * 9 + dx;
                float w0 = bf[tt], w1 = bf[81 + tt], w2 = bf[162 + tt], w3 = bf[243 + tt];
                #pragma unroll
                for (int p = 0; p < 4; ++p) {
                    acc[p][0] = fmaf4(w0, v[p + dx], acc[p][0]);
                    acc[p][1] = fmaf4(w1, v[p + dx], acc[p][1]);
                    acc[p][2] = fmaf4(w2, v[p + dx], acc[p][2]);
                    acc[p][3] = fmaf4(w3, v[p + dx], acc[p][3]);
                }
            }
            row += Wp * 4;
        }
        #pragma unroll
        for (int p = 0; p < 4; ++p) {
            size_t idx = ((size_t)(n * W + y) * W + x0 + p) * 4 + c4;
            nt_store(&b0[idx], acc[p][0]);
            nt_store(&b1[idx], acc[p][1]);
            nt_store(&b2[idx], acc[p][2]);
            nt_store(&b3[idx], acc[p][3]);
        }
    } else {
        const int Wo = W >> 1;
        int q2 = q - bandsPerN;
        int xg = (t >> 2) & (Wo / 4 - 1);
        int ry = t >> (LOGW - 1);            // rows-per-block = 256/Wo
        int yo = q2 * (256 >> (LOGW - 1)) + ry;
        int xo0 = xg * 4;
        const float4* row = in + ((size_t)(n * Wp + 2 * yo) * Wp + 2 * xo0) * 4 + c4;

        float4 acc[4];
        #pragma unroll
        for (int p = 0; p < 4; ++p) acc[p] = f4z();

        #pragma unroll 1
        for (int dy = 0; dy < 17; ++dy) {
            float4 v[23];
            #pragma unroll
            for (int j = 0; j < 23; ++j) v[j] = row[j * 4];
            #pragma unroll
            for (int dx = 0; dx < 17; ++dx) {
                float w = lf[dy * 17 + dx];
                #pragma unroll
                for (int p = 0; p < 4; ++p)
                    acc[p] = fmaf4(w, v[2 * p + dx], acc[p]);
            }
            row += Wp * 4;
        }
        int W1 = Wo + 2 * outPad;
        #pragma unroll
        for (int p = 0; p < 4; ++p)
            nt_store(&lo_out[((size_t)(n * W1 + yo + outPad) * W1 + xo0 + p + outPad) * 4 + c4],
                     acc[p]);
    }
}

// ---------------------------------------------------------------- launch

extern "C" void kernel_launch(void* const* d_in, const int* in_sizes, int n_in,
                              void* d_out, int out_size, void* d_ws, size_t ws_size,
                              hipStream_t stream) {
    const float* image   = (const float*)d_in[0];
    const float* lo0filt = (const float*)d_in[1];
    const float* hi0filt = (const float*)d_in[2];
    const float* lofilt  = (const float*)d_in[3];
    const float* bfilts  = (const float*)d_in[4];
    float* out = (float*)d_out;
    float* ws  = (float*)d_ws;

    const int N = 8, C = 16;
    size_t sz[5];
    const int Ws[5] = {256, 128, 64, 32, 16};
    for (int s = 0; s < 5; ++s) sz[s] = (size_t)N * Ws[s] * Ws[s] * C;

    // Workspace: P0 = image pad4 (264^2); L0..L3 = lo0..lo3 pad8.
    float* P0 = ws;
    float* L0 = P0 + (size_t)N * 264 * 264 * C;
    float* L1 = L0 + (size_t)N * 272 * 272 * C;
    float* L2 = L1 + (size_t)N * 144 * 144 * C;
    float* L3 = L2 + (size_t)N * 80 * 80 * C;

    // Output layout (reversed pyramid, flat):
    // [ lo_final | s=3 b=3..0 | s=2 b=3..0 | s=1 b=3..0 | s=0 b=3..0 | hi0 ]
    float* out_lofinal = out;
    size_t o = sz[4];
    float* band_ptr[4][4];
    for (int s = 3; s >= 0; --s)
        for (int b = 3; b >= 0; --b) { band_ptr[s][b] = out + o; o += sz[s]; }
    float* out_hi0 = out + o;

    // 1. zero pad borders of L0..L3 (single launch)
    zero_pads_all<<<2048, 256, 0, stream>>>(
        (float4*)L0, (float4*)L1, (float4*)L2, (float4*)L3);
    // 2. image -> P0 (pad 4); 1089 blocks per image, n = b&7
    pad_copy_img<<<8 * 1089, 256, 0, stream>>>(
        (const float4*)image, (float4*)P0);
    // 3. hi0 (flat) + lo0 (L0) from P0; one y row per block, n = b&7
    conv9_dual4<<<2048, 256, 0, stream>>>(
        (const float4*)P0, (float4*)out_hi0, (float4*)L0, hi0filt, lo0filt);
    // 4..7. per-scale fused: bands_s + lo_{s+1}; grid = 8*(bandsPerN + downPerN)
    scale_fused<8><<<8 * (256 + 64), 256, 0, stream>>>(
        (const float4*)L0, (float4*)band_ptr[0][0], (float4*)band_ptr[0][1],
        (float4*)band_ptr[0][2], (float4*)band_ptr[0][3], (float4*)L1,
        bfilts, lofilt, 8);
    scale_fused<7><<<8 * (64 + 16), 256, 0, stream>>>(
        (const float4*)L1, (float4*)band_ptr[1][0], (float4*)band_ptr[1][1],
        (float4*)band_ptr[1][2], (float4*)band_ptr[1][3], (float4*)L2,
        bfilts, lofilt, 8);
    scale_fused<6><<<8 * (16 + 4), 256, 0, stream>>>(
        (const float4*)L2, (float4*)band_ptr[2][0], (float4*)band_ptr[2][1],
        (float4*)band_ptr[2][2], (float4*)band_ptr[2][3], (float4*)L3,
        bfilts, lofilt, 8);
    scale_fused<5><<<8 * (4 + 1), 256, 0, stream>>>(
        (const float4*)L3, (float4*)band_ptr[3][0], (float4*)band_ptr[3][1],
        (float4*)band_ptr[3][2], (float4*)band_ptr[3][3], (float4*)out_lofinal,
        bfilts, lofilt, 0);
}

// Round 7
// 224.937 us; speedup vs baseline: 1.0471x; 1.0471x over previous
//
#include <hip/hip_runtime.h>

// Steerable pyramid, depthwise convs, NHWC fp32, C=16 (= 4 x float4).
// Branch-free convs over zero-padded workspace buffers.
// 4 output pixels per thread (sliding-window column reuse).
// XCD-aware scheduling: n = blockIdx & 7, y swept in order per XCD.
// Non-temporal stores for all conv outputs (no L2 write-allocate thrash).
// NEW: explicit software pipeline — ping-pong row buffers (va/vb) so the
// loads of row dy+1 are in flight during the FMAs of row dy. All buffer
// indexing is compile-time static (unroll-2 pairing).

static __device__ __forceinline__ float4 f4z() { return make_float4(0.f, 0.f, 0.f, 0.f); }

static __device__ __forceinline__ float4 fmaf4(float f, float4 v, float4 a) {
    a.x = fmaf(f, v.x, a.x);
    a.y = fmaf(f, v.y, a.y);
    a.z = fmaf(f, v.z, a.z);
    a.w = fmaf(f, v.w, a.w);
    return a;
}

typedef __attribute__((ext_vector_type(4))) float f32x4;

static __device__ __forceinline__ void nt_store(float4* p, float4 v) {
    __builtin_nontemporal_store(*(const f32x4*)&v, (f32x4*)p);
}

// ---------------------------------------------------------------- pad helpers

// Copy 256x256 image into 264x264 buffer (pad 4), zero border. n = b&7.
__global__ __launch_bounds__(256) void pad_copy_img(
    const float4* __restrict__ src, float4* __restrict__ dst)
{
    const int W = 256, P = 4, Wp = 264;
    int n = blockIdx.x & 7;
    int q = blockIdx.x >> 3;                 // 1089 per n
    int e = q * 256 + threadIdx.x;           // < 264*264*4 exactly
    int c4 = e & 3;
    int pix = e >> 2;                        // < 264*264
    int yp = pix / Wp;
    int xp = pix - yp * Wp;
    int y = yp - P, x = xp - P;
    bool ok = ((unsigned)y < (unsigned)W) && ((unsigned)x < (unsigned)W);
    int yc = min(max(y, 0), W - 1), xc = min(max(x, 0), W - 1);
    float4 v = src[(((n * W + yc) * W + xc) << 2) + c4];
    if (!ok) v = f4z();
    dst[((size_t)n * Wp * Wp + pix) * 4 + c4] = v;
}

// Zero the 8-wide pad borders of all four lo buffers in ONE launch.
__global__ __launch_bounds__(256) void zero_pads_all(
    float4* __restrict__ L0, float4* __restrict__ L1,
    float4* __restrict__ L2, float4* __restrict__ L3)
{
    int b = blockIdx.x;
    float4* buf; int W;
    if (b < 1056)      { buf = L0; W = 256; }
    else if (b < 1600) { buf = L1; W = 128; b -= 1056; }
    else if (b < 1888) { buf = L2; W = 64;  b -= 1600; }
    else               { buf = L3; W = 32;  b -= 1888; }
    int Wp = W + 16;
    int perN = 16 * Wp + 16 * W;
    int tid = b * 256 + threadIdx.x;
    int c4 = tid & 3;
    int p  = tid >> 2;
    int n  = p / perN;
    int r  = p - n * perN;
    int y, x;
    if (r < 16 * Wp) {
        int row = r / Wp;
        x = r - row * Wp;
        y = (row < 8) ? row : (W + row);
    } else {
        int q = r - 16 * Wp;
        y = 8 + (q >> 4);
        int xi = q & 15;
        x = (xi < 8) ? xi : (Wp - 16 + xi);
    }
    buf[((size_t)(n * Wp + y) * Wp + x) * 4 + c4] = f4z();
}

// ---------------------------------------------------------------- convs

#define LOADROW12(dst, ptr)                         \
    _Pragma("unroll")                               \
    for (int j = 0; j < 12; ++j) dst[j] = (ptr)[j * 4];

#define LOADROW23(dst, ptr)                         \
    _Pragma("unroll")                               \
    for (int j = 0; j < 23; ++j) dst[j] = (ptr)[j * 4];

// hi0 + lo0 from padded image (pad 4). 4 px/thread. One y row per block.
__global__ __launch_bounds__(256) void conv9_dual4(
    const float4* __restrict__ in,   // 264 wide, pad 4
    float4* __restrict__ hi0,        // flat 256
    float4* __restrict__ lo0,        // 272 wide, pad 8
    const float* __restrict__ fh, const float* __restrict__ fl)
{
    const int W = 256, Wp = 264;
    int n = blockIdx.x & 7;
    int y = blockIdx.x >> 3;
    int t = threadIdx.x;
    int c4 = t & 3;
    int xg = t >> 2;                 // 0..63
    int x0 = xg * 4;
    const float4* rp = in + ((size_t)(n * Wp + y) * Wp + x0) * 4 + c4;
    const size_t rstep = (size_t)Wp * 4;

    float4 ah[4], al[4];
    #pragma unroll
    for (int p = 0; p < 4; ++p) { ah[p] = f4z(); al[p] = f4z(); }

    float4 va[12], vb[12];
    LOADROW12(va, rp); rp += rstep;

#define DUAL_ROW(buf, dy)                                   \
    {                                                       \
        const float* fhp = fh + (dy) * 9;                   \
        const float* flp = fl + (dy) * 9;                   \
        _Pragma("unroll")                                   \
        for (int dx = 0; dx < 9; ++dx) {                    \
            float wh = fhp[dx], wl = flp[dx];               \
            _Pragma("unroll")                               \
            for (int p = 0; p < 4; ++p) {                   \
                ah[p] = fmaf4(wh, buf[p + dx], ah[p]);      \
                al[p] = fmaf4(wl, buf[p + dx], al[p]);      \
            }                                               \
        }                                                   \
    }

    #pragma unroll 1
    for (int d2 = 0; d2 < 4; ++d2) {
        int dy0 = 2 * d2;
        LOADROW12(vb, rp); rp += rstep;
        DUAL_ROW(va, dy0);
        LOADROW12(va, rp); rp += rstep;
        DUAL_ROW(vb, dy0 + 1);
    }
    DUAL_ROW(va, 8);
#undef DUAL_ROW

    #pragma unroll
    for (int p = 0; p < 4; ++p) {
        nt_store(&hi0[((size_t)(n * W + y) * W + x0 + p) * 4 + c4], ah[p]);
        nt_store(&lo0[((size_t)(n * 272 + y + 8) * 272 + x0 + p + 8) * 4 + c4], al[p]);
    }
}

// Fused per-scale kernel. n = b&7; q = b>>3. q < bandsPerN -> 9x9 quad bands,
// else 17x17 stride-2 downsample. Input: padded (pad 8) lo, Wp = W+16.
template <int LOGW>
__global__ __launch_bounds__(256) void scale_fused(
    const float4* __restrict__ in,
    float4* __restrict__ b0, float4* __restrict__ b1,
    float4* __restrict__ b2, float4* __restrict__ b3,
    float4* __restrict__ lo_out,
    const float* __restrict__ bf,    // 4*81 contiguous
    const float* __restrict__ lf,    // 17*17
    int outPad)
{
    const int W = 1 << LOGW, Wp = W + 16;
    const int bandsPerN = (W * W) >> 8;      // blocks per image for bands
    int n = blockIdx.x & 7;
    int q = blockIdx.x >> 3;
    int t = threadIdx.x;
    int c4 = t & 3;

    if (q < bandsPerN) {
        int xg = (t >> 2) & (W / 4 - 1);
        int ry = t >> LOGW;                  // rows-per-block = 256/W
        int y  = q * (256 >> LOGW) + ry;
        int x0 = xg * 4;
        const float4* rp = in + ((size_t)(n * Wp + y + 4) * Wp + (x0 + 4)) * 4 + c4;
        const size_t rstep = (size_t)Wp * 4;

        float4 acc[4][4];                    // [pixel][filter]
        #pragma unroll
        for (int p = 0; p < 4; ++p)
            #pragma unroll
            for (int f = 0; f < 4; ++f) acc[p][f] = f4z();

        float4 va[12], vb[12];
        LOADROW12(va, rp); rp += rstep;

#define QUAD_ROW(buf, dy)                                       \
    {                                                           \
        const float* wp = bf + (dy) * 9;                        \
        _Pragma("unroll")                                       \
        for (int dx = 0; dx < 9; ++dx) {                        \
            float w0 = wp[dx], w1 = wp[81 + dx];                \
            float w2 = wp[162 + dx], w3 = wp[243 + dx];         \
            _Pragma("unroll")                                   \
            for (int p = 0; p < 4; ++p) {                       \
                acc[p][0] = fmaf4(w0, buf[p + dx], acc[p][0]);  \
                acc[p][1] = fmaf4(w1, buf[p + dx], acc[p][1]);  \
                acc[p][2] = fmaf4(w2, buf[p + dx], acc[p][2]);  \
                acc[p][3] = fmaf4(w3, buf[p + dx], acc[p][3]);  \
            }                                                   \
        }                                                       \
    }

        #pragma unroll 1
        for (int d2 = 0; d2 < 4; ++d2) {
            int dy0 = 2 * d2;
            LOADROW12(vb, rp); rp += rstep;
            QUAD_ROW(va, dy0);
            LOADROW12(va, rp); rp += rstep;
            QUAD_ROW(vb, dy0 + 1);
        }
        QUAD_ROW(va, 8);
#undef QUAD_ROW

        #pragma unroll
        for (int p = 0; p < 4; ++p) {
            size_t idx = ((size_t)(n * W + y) * W + x0 + p) * 4 + c4;
            nt_store(&b0[idx], acc[p][0]);
            nt_store(&b1[idx], acc[p][1]);
            nt_store(&b2[idx], acc[p][2]);
            nt_store(&b3[idx], acc[p][3]);
        }
    } else {
        const int Wo = W >> 1;
        int q2 = q - bandsPerN;
        int xg = (t >> 2) & (Wo / 4 - 1);
        int ry = t >> (LOGW - 1);            // rows-per-block = 256/Wo
        int yo = q2 * (256 >> (LOGW - 1)) + ry;
        int xo0 = xg * 4;
        const float4* rp = in + ((size_t)(n * Wp + 2 * yo) * Wp + 2 * xo0) * 4 + c4;
        const size_t rstep = (size_t)Wp * 4;

        float4 acc[4];
        #pragma unroll
        for (int p = 0; p < 4; ++p) acc[p] = f4z();

        float4 va[23], vb[23];
        LOADROW23(va, rp); rp += rstep;

#define DOWN_ROW(buf, dy)                                       \
    {                                                           \
        const float* wp = lf + (dy) * 17;                       \
        _Pragma("unroll")                                       \
        for (int dx = 0; dx < 17; ++dx) {                       \
            float w = wp[dx];                                   \
            _Pragma("unroll")                                   \
            for (int p = 0; p < 4; ++p)                         \
                acc[p] = fmaf4(w, buf[2 * p + dx], acc[p]);     \
        }                                                       \
    }

        #pragma unroll 1
        for (int d2 = 0; d2 < 8; ++d2) {
            int dy0 = 2 * d2;
            LOADROW23(vb, rp); rp += rstep;
            DOWN_ROW(va, dy0);
            LOADROW23(va, rp); rp += rstep;
            DOWN_ROW(vb, dy0 + 1);
        }
        DOWN_ROW(va, 16);
#undef DOWN_ROW

        int W1 = Wo + 2 * outPad;
        #pragma unroll
        for (int p = 0; p < 4; ++p)
            nt_store(&lo_out[((size_t)(n * W1 + yo + outPad) * W1 + xo0 + p + outPad) * 4 + c4],
                     acc[p]);
    }
}

// ---------------------------------------------------------------- launch

extern "C" void kernel_launch(void* const* d_in, const int* in_sizes, int n_in,
                              void* d_out, int out_size, void* d_ws, size_t ws_size,
                              hipStream_t stream) {
    const float* image   = (const float*)d_in[0];
    const float* lo0filt = (const float*)d_in[1];
    const float* hi0filt = (const float*)d_in[2];
    const float* lofilt  = (const float*)d_in[3];
    const float* bfilts  = (const float*)d_in[4];
    float* out = (float*)d_out;
    float* ws  = (float*)d_ws;

    const int N = 8, C = 16;
    size_t sz[5];
    const int Ws[5] = {256, 128, 64, 32, 16};
    for (int s = 0; s < 5; ++s) sz[s] = (size_t)N * Ws[s] * Ws[s] * C;

    // Workspace: P0 = image pad4 (264^2); L0..L3 = lo0..lo3 pad8.
    float* P0 = ws;
    float* L0 = P0 + (size_t)N * 264 * 264 * C;
    float* L1 = L0 + (size_t)N * 272 * 272 * C;
    float* L2 = L1 + (size_t)N * 144 * 144 * C;
    float* L3 = L2 + (size_t)N * 80 * 80 * C;

    // Output layout (reversed pyramid, flat):
    // [ lo_final | s=3 b=3..0 | s=2 b=3..0 | s=1 b=3..0 | s=0 b=3..0 | hi0 ]
    float* out_lofinal = out;
    size_t o = sz[4];
    float* band_ptr[4][4];
    for (int s = 3; s >= 0; --s)
        for (int b = 3; b >= 0; --b) { band_ptr[s][b] = out + o; o += sz[s]; }
    float* out_hi0 = out + o;

    // 1. zero pad borders of L0..L3 (single launch)
    zero_pads_all<<<2048, 256, 0, stream>>>(
        (float4*)L0, (float4*)L1, (float4*)L2, (float4*)L3);
    // 2. image -> P0 (pad 4); 1089 blocks per image, n = b&7
    pad_copy_img<<<8 * 1089, 256, 0, stream>>>(
        (const float4*)image, (float4*)P0);
    // 3. hi0 (flat) + lo0 (L0) from P0; one y row per block, n = b&7
    conv9_dual4<<<2048, 256, 0, stream>>>(
        (const float4*)P0, (float4*)out_hi0, (float4*)L0, hi0filt, lo0filt);
    // 4..7. per-scale fused: bands_s + lo_{s+1}; grid = 8*(bandsPerN + downPerN)
    scale_fused<8><<<8 * (256 + 64), 256, 0, stream>>>(
        (const float4*)L0, (float4*)band_ptr[0][0], (float4*)band_ptr[0][1],
        (float4*)band_ptr[0][2], (float4*)band_ptr[0][3], (float4*)L1,
        bfilts, lofilt, 8);
    scale_fused<7><<<8 * (64 + 16), 256, 0, stream>>>(
        (const float4*)L1, (float4*)band_ptr[1][0], (float4*)band_ptr[1][1],
        (float4*)band_ptr[1][2], (float4*)band_ptr[1][3], (float4*)L2,
        bfilts, lofilt, 8);
    scale_fused<6><<<8 * (16 + 4), 256, 0, stream>>>(
        (const float4*)L2, (float4*)band_ptr[2][0], (float4*)band_ptr[2][1],
        (float4*)band_ptr[2][2], (float4*)band_ptr[2][3], (float4*)L3,
        bfilts, lofilt, 8);
    scale_fused<5><<<8 * (4 + 1), 256, 0, stream>>>(
        (const float4*)L3, (float4*)band_ptr[3][0], (float4*)band_ptr[3][1],
        (float4*)band_ptr[3][2], (float4*)band_ptr[3][3], (float4*)out_lofinal,
        bfilts, lofilt, 0);
}